// Round 11
// baseline (153.293 us; speedup 1.0000x reference)
//
#include <hip/hip_runtime.h>
#include <hip/hip_bf16.h>

// ConvMosaic via bf16 MFMA — ABLATION ROUND on the r4 structure.
// y[n,co,h,w] = sum_{c,di,dj} x[n,c,h+di-1,w+dj-1] * W[w%16, c*9+di*3+dj, co]
// Three dispatches of template<int V> conv_mosaic_mfma:
//   V bit0 = real B global-loads (else constant frag)
//   V bit1 = real A LDS ds_reads (else constant frag; staging kept alive via asm)
//   launch order: conv<2> (noB), conv<1> (noA), conv<3> (full, LAST -> d_out correct).
// Purpose: r4-r10 all land at 60-67us with every pipe <25% busy across five
// structurally different kernels; per-dispatch dur of the ablated variants
// tells us which load path (global B vs LDS A vs staging skeleton) carries
// the serialized latency.

using bf16 = __hip_bfloat16;
typedef __attribute__((ext_vector_type(8))) short bf16x8_t;  // A/B frag: 8 bf16 (4 VGPR)
typedef __attribute__((ext_vector_type(4))) float f32x4_t;   // C/D frag

constexpr int NB    = 4;
constexpr int C_IN  = 32;
constexpr int HH    = 256;
constexpr int WW    = 256;
constexpr int C_OUT = 64;
constexpr int SPE   = 16;

constexpr int TH = 16;          // tile height (== MFMA M)
constexpr int TW = 32;          // tile width (w and w+16 share s = w%16)
constexpr int XR = TH + 2;      // 18
constexpr int XC = TW + 2;      // 34
constexpr int CPAD = 40;        // c-dim padded 32->40: 80 B col stride (16B-aligned)

// ---- pre-pass: W[s][c*9+tap][co] f32 -> W_t[s][co][tap*32+c] bf16 ----
__global__ __launch_bounds__(256)
void prep_weights(const float* __restrict__ w, bf16* __restrict__ wt) {
    int idx = blockIdx.x * 256 + threadIdx.x;  // 16*64*288 total
    if (idx >= SPE * C_OUT * 288) return;
    int s  = idx / (C_OUT * 288);
    int r  = idx % (C_OUT * 288);
    int co = r / 288;
    int kk = r % 288;            // kk = tap*32 + c
    int tap = kk >> 5;
    int c   = kk & 31;
    float v = w[((size_t)s * 288 + c * 9 + tap) * C_OUT + co];
    wt[idx] = __float2bfloat16(v);
}

template<int V>
__global__ __launch_bounds__(1024, 4)
void conv_mosaic_mfma(const float* __restrict__ x,
                      const bf16* __restrict__ wt,
                      float* __restrict__ out) {
    __shared__ __align__(16) bf16 xs[XR * XC * CPAD];  // 18*34*40*2 = 48960 B

    const int n  = blockIdx.y;
    const int tw = blockIdx.x & 7;    // 8 w-tiles
    const int th = blockIdx.x >> 3;   // 16 h-tiles
    const int h0 = th * TH;
    const int w0 = tw * TW;
    const int t  = threadIdx.x;

    // ---- stage x tile (zero-padded halo), f32 -> bf16, layout [row][col][c] ----
    const float* xn = x + (size_t)n * C_IN * HH * WW;
    constexpr int VJOBS = C_IN * XR * 8;  // 4608
#pragma unroll
    for (int it = 0; it < 5; ++it) {
        const int idx = t + it * 1024;
        if (idx < VJOBS) {
            const int c  = idx / (XR * 8);
            const int rr = idx % (XR * 8);
            const int r  = rr >> 3;
            const int q  = rr & 7;
            const int gh = h0 + r - 1;
            float4 v = make_float4(0.f, 0.f, 0.f, 0.f);
            if (gh >= 0 && gh < HH)
                v = *reinterpret_cast<const float4*>(
                    &xn[((size_t)c * HH + gh) * WW + w0 + q * 4]);
            bf16* d = &xs[(r * XC + q * 4 + 1) * CPAD + c];
            d[0]        = __float2bfloat16(v.x);
            d[CPAD]     = __float2bfloat16(v.y);
            d[2 * CPAD] = __float2bfloat16(v.z);
            d[3 * CPAD] = __float2bfloat16(v.w);
        }
    }
    // halo edge cols 0 and 33 (scalar, bounds-checked in h and w)
    constexpr int EJOBS = C_IN * XR * 2;  // 1152
#pragma unroll
    for (int it = 0; it < 2; ++it) {
        const int idx = t + it * 1024;
        if (idx < EJOBS) {
            const int c   = idx / (XR * 2);
            const int rr  = idx % (XR * 2);
            const int r   = rr >> 1;
            const int e   = rr & 1;
            const int col = e ? 33 : 0;
            const int gh  = h0 + r - 1;
            const int gw  = w0 + (e ? 32 : -1);
            float vv = 0.f;
            if (gh >= 0 && gh < HH && gw >= 0 && gw < WW)
                vv = xn[((size_t)c * HH + gh) * WW + gw];
            xs[(r * XC + col) * CPAD + c] = __float2bfloat16(vv);
        }
    }
    __syncthreads();

    // keep staging alive when A-path is ablated (rule #17: anti-DCE)
    if constexpr (!(V & 2)) {
        short tok = reinterpret_cast<const short*>(xs)[t];
        asm volatile("" :: "v"((int)tok));
    }

    // 16 waves: wave = s-group (wave&3) x c_out tile (wave>>2)
    const int wave = t >> 6;
    const int lane = t & 63;
    const int g    = wave & 3;    // s = g*4 + si
    const int ct   = wave >> 2;   // co tile: co = ct*16 + lm
    const int lm   = lane & 15;   // A: row m (h). B/D: col n (co).
    const int lg   = lane >> 4;   // k-group; D row group

    // constant fragment (bf16 1.0 in every slot) for ablated paths
    bf16x8_t cfr;
#pragma unroll
    for (int j = 0; j < 8; ++j) cfr[j] = (short)0x3F80;

    // persistent accumulators: [wm][si], si packs 4 consecutive w
    f32x4_t dacc[2][4];
#pragma unroll
    for (int b = 0; b < 2; ++b)
#pragma unroll
        for (int c = 0; c < 4; ++c) dacc[b][c] = (f32x4_t){0.f, 0.f, 0.f, 0.f};

#pragma unroll
    for (int si = 0; si < 4; ++si) {
        const int s = g * 4 + si;

        bf16x8_t bfr[9];
        if constexpr (V & 1) {
            const bf16* bp = wt + ((size_t)(s * C_OUT + ct * 16 + lm) * 288 + lg * 8);
#pragma unroll
            for (int tap = 0; tap < 9; ++tap)
                bfr[tap] = *reinterpret_cast<const bf16x8_t*>(bp + tap * 32);
        } else {
#pragma unroll
            for (int tap = 0; tap < 9; ++tap) bfr[tap] = cfr;
        }

        const bf16* ap = &xs[(lm * XC + s) * CPAD + lg * 8];
#pragma unroll
        for (int tap = 0; tap < 9; ++tap) {
            const int di = tap / 3, dj = tap % 3;
            bf16x8_t a0, a1;
            if constexpr (V & 2) {
                a0 = *reinterpret_cast<const bf16x8_t*>(ap + (di * XC + dj) * CPAD);
                a1 = *reinterpret_cast<const bf16x8_t*>(ap + (di * XC + dj + 16) * CPAD);
            } else {
                a0 = cfr;
                a1 = cfr;
            }
            dacc[0][si] = __builtin_amdgcn_mfma_f32_16x16x32_bf16(a0, bfr[tap], dacc[0][si], 0, 0, 0);
            dacc[1][si] = __builtin_amdgcn_mfma_f32_16x16x32_bf16(a1, bfr[tap], dacc[1][si], 0, 0, 0);
        }
    }

    // ---- store: float4 across si (4 consecutive w) ----
    const int co = ct * 16 + lm;
#pragma unroll
    for (int wm = 0; wm < 2; ++wm) {
#pragma unroll
        for (int j = 0; j < 4; ++j) {
            const int h = h0 + lg * 4 + j;
            float4 v = make_float4(dacc[wm][0][j], dacc[wm][1][j],
                                   dacc[wm][2][j], dacc[wm][3][j]);
            *reinterpret_cast<float4*>(
                &out[(((size_t)n * C_OUT + co) * HH + h) * WW + w0 + g * 4 + wm * 16]) = v;
        }
    }
}

extern "C" void kernel_launch(void* const* d_in, const int* in_sizes, int n_in,
                              void* d_out, int out_size, void* d_ws, size_t ws_size,
                              hipStream_t stream) {
    const float* x = (const float*)d_in[0];
    const float* w = (const float*)d_in[1];
    float* out     = (float*)d_out;
    bf16* wt       = (bf16*)d_ws;   // 16*64*288*2 = 589824 B

    prep_weights<<<(SPE * C_OUT * 288 + 255) / 256, 256, 0, stream>>>(w, wt);

    dim3 grid((WW / TW) * (HH / TH), NB);  // (8*16, 4) = 512 blocks

    // Ablation dispatches (outputs overwritten by the final full kernel):
    conv_mosaic_mfma<2><<<grid, 1024, 0, stream>>>(x, wt, out);  // A real, B const
    conv_mosaic_mfma<1><<<grid, 1024, 0, stream>>>(x, wt, out);  // B real, A const
    // Full kernel LAST -> d_out deterministic and correct:
    conv_mosaic_mfma<3><<<grid, 1024, 0, stream>>>(x, wt, out);
}

// Round 12
// 85.442 us; speedup vs baseline: 1.7941x; 1.7941x over previous
//
#include <hip/hip_runtime.h>
#include <hip/hip_bf16.h>

// ConvMosaic via bf16 MFMA.
// y[n,co,h,w] = sum_{c,di,dj} x[n,c,h+di-1,w+dj-1] * W[w%16, c*9+di*3+dj, co]
// v12: phase-blending. r11 ablation: A-loads and B-loads are FREE (noA/noB/full
//   all ~56us). The 56us = 2 generations x (read-burst 7.6us + compute gap
//   ~10us + write-burst 10us) with zero overlap (barrier-lockstep phases).
//   Fixes: (a) eager per-si stores -> write burst spreads into compute phase;
//   (b) 8h x 32w tiles, 1024 blocks x 512thr, 27KB LDS -> 4 blocks/CU resident
//   (32 waves, full occupancy), single generation, shorter read burst.
//   M-row m -> pixel (h = h0+(m&7), w = w0 + s + 16*(m>>3)); same s-class since
//   w0%32==0. Fragment math identical to verified r4/r6 kernels.

using bf16 = __hip_bfloat16;
typedef __attribute__((ext_vector_type(8))) short bf16x8_t;  // A/B frag: 8 bf16
typedef __attribute__((ext_vector_type(4))) float f32x4_t;   // C/D frag

constexpr int NB    = 4;
constexpr int C_IN  = 32;
constexpr int HH    = 256;
constexpr int WW    = 256;
constexpr int C_OUT = 64;
constexpr int SPE   = 16;

constexpr int TH = 8;           // tile height (M packs 8h x 2 w-halves)
constexpr int TW = 32;          // tile width (full-line stores)
constexpr int XR = TH + 2;      // 10
constexpr int XC = TW + 2;      // 34
constexpr int CPAD = 40;        // c-dim padded 32->40: 80 B col stride (16B-aligned)

// ---- pre-pass: W[s][c*9+tap][co] f32 -> W_t[s][co][tap*32+c] bf16 ----
__global__ __launch_bounds__(256)
void prep_weights(const float* __restrict__ w, bf16* __restrict__ wt) {
    int idx = blockIdx.x * 256 + threadIdx.x;  // 16*64*288 total
    if (idx >= SPE * C_OUT * 288) return;
    int s  = idx / (C_OUT * 288);
    int r  = idx % (C_OUT * 288);
    int co = r / 288;
    int kk = r % 288;            // kk = tap*32 + c
    int tap = kk >> 5;
    int c   = kk & 31;
    float v = w[((size_t)s * 288 + c * 9 + tap) * C_OUT + co];
    wt[idx] = __float2bfloat16(v);
}

__global__ __launch_bounds__(512, 8)
void conv_mosaic_mfma(const float* __restrict__ x,
                      const bf16* __restrict__ wt,
                      float* __restrict__ out) {
    __shared__ __align__(16) bf16 xs[XR * XC * CPAD];  // 10*34*40*2 = 27200 B

    const int n  = blockIdx.y;
    const int tw = blockIdx.x & 7;    // 8 w-tiles
    const int th = blockIdx.x >> 3;   // 32 h-tiles
    const int h0 = th * TH;
    const int w0 = tw * TW;
    const int t  = threadIdx.x;

    // ---- stage x tile (zero-padded halo), f32 -> bf16, layout [row][col][c] ----
    const float* xn = x + (size_t)n * C_IN * HH * WW;
    constexpr int VJOBS = C_IN * XR * 8;  // 2560
#pragma unroll
    for (int it = 0; it < 5; ++it) {
        const int idx = t + it * 512;
        if (idx < VJOBS) {
            const int c  = idx / (XR * 8);
            const int rr = idx % (XR * 8);
            const int r  = rr >> 3;
            const int q  = rr & 7;
            const int gh = h0 + r - 1;
            float4 v = make_float4(0.f, 0.f, 0.f, 0.f);
            if (gh >= 0 && gh < HH)
                v = *reinterpret_cast<const float4*>(
                    &xn[((size_t)c * HH + gh) * WW + w0 + q * 4]);
            bf16* d = &xs[(r * XC + q * 4 + 1) * CPAD + c];
            d[0]        = __float2bfloat16(v.x);
            d[CPAD]     = __float2bfloat16(v.y);
            d[2 * CPAD] = __float2bfloat16(v.z);
            d[3 * CPAD] = __float2bfloat16(v.w);
        }
    }
    // halo edge cols 0 and 33 (scalar, bounds-checked in h and w)
    constexpr int EJOBS = C_IN * XR * 2;  // 640
#pragma unroll
    for (int it = 0; it < 2; ++it) {
        const int idx = t + it * 512;
        if (idx < EJOBS) {
            const int c   = idx / (XR * 2);
            const int rr  = idx % (XR * 2);
            const int r   = rr >> 1;
            const int e   = rr & 1;
            const int col = e ? 33 : 0;
            const int gh  = h0 + r - 1;
            const int gw  = w0 + (e ? 32 : -1);
            float vv = 0.f;
            if (gh >= 0 && gh < HH && gw >= 0 && gw < WW)
                vv = xn[((size_t)c * HH + gh) * WW + gw];
            xs[(r * XC + col) * CPAD + c] = __float2bfloat16(vv);
        }
    }
    __syncthreads();

    // 8 waves: wave = s-group (wave&3) x ct-half (wave>>2)
    const int wave = t >> 6;
    const int lane = t & 63;
    const int g    = wave & 3;    // s = g*4 + si
    const int cth  = wave >> 2;   // ct = cth*2 + ctl
    const int lm   = lane & 15;   // A row m / B,D col (co)
    const int lg   = lane >> 4;   // k-group; D row group

    // M-row m = lm -> pixel (h = h0 + (m&7), w-half = m>>3)
    const int arow = lm & 7;      // A h-row offset
    const int awh  = lm >> 3;     // A w-half
    // D rows: r = 4*lg + j -> h-off = (4*(lg&1)+j), w-half = lg>>1
    const int dh   = (lg & 1) * 4;
    const int dwh  = lg >> 1;

#pragma unroll
    for (int si = 0; si < 4; ++si) {
        const int s = g * 4 + si;

        // A fragments for this si: 9 taps (shared across both ct)
        bf16x8_t afr[9];
        const bf16* ap = &xs[((arow) * XC + s + 16 * awh) * CPAD + lg * 8];
#pragma unroll
        for (int tap = 0; tap < 9; ++tap) {
            const int di = tap / 3, dj = tap % 3;
            afr[tap] = *reinterpret_cast<const bf16x8_t*>(ap + (di * XC + dj) * CPAD);
        }

#pragma unroll
        for (int ctl = 0; ctl < 2; ++ctl) {
            const int ct = cth * 2 + ctl;
            const bf16* bp = wt + ((size_t)(s * C_OUT + ct * 16 + lm) * 288 + lg * 8);
            f32x4_t dacc = {0.f, 0.f, 0.f, 0.f};
#pragma unroll
            for (int tap = 0; tap < 9; ++tap) {
                bf16x8_t bfr = *reinterpret_cast<const bf16x8_t*>(bp + tap * 32);
                dacc = __builtin_amdgcn_mfma_f32_16x16x32_bf16(afr[tap], bfr, dacc, 0, 0, 0);
            }
            // eager store: spread the write burst into the compute phase
            const int co = ct * 16 + lm;
            const int w  = w0 + s + 16 * dwh;
#pragma unroll
            for (int j = 0; j < 4; ++j) {
                const int h = h0 + dh + j;
                out[(((size_t)n * C_OUT + co) * HH + h) * WW + w] = dacc[j];
            }
        }
    }
}

extern "C" void kernel_launch(void* const* d_in, const int* in_sizes, int n_in,
                              void* d_out, int out_size, void* d_ws, size_t ws_size,
                              hipStream_t stream) {
    const float* x = (const float*)d_in[0];
    const float* w = (const float*)d_in[1];
    float* out     = (float*)d_out;
    bf16* wt       = (bf16*)d_ws;   // 16*64*288*2 = 589824 B

    prep_weights<<<(SPE * C_OUT * 288 + 255) / 256, 256, 0, stream>>>(w, wt);

    dim3 grid((WW / TW) * (HH / TH), NB);  // (8*32, 4) = 1024 blocks
    conv_mosaic_mfma<<<grid, 512, 0, stream>>>(x, wt, out);
}